// Round 4
// baseline (1435.636 us; speedup 1.0000x reference)
//
#include <hip/hip_runtime.h>
#include <math.h>

// Problem constants
#define B_   32
#define H_   512
#define W_   512
#define C_   3
#define M_   96          // B_*C_
#define NW_  263         // floor((512+15)/2)
#define NH_  263
#define DETPER 69169     // 263*263
#define DETTOT 207507    // 3*DETPER
#define DETSTRIDE 207508 // padded to multiple of 4 for float4 alignment
#define NVEC 51876       // DETTOT/4 (floor); tail = 3 elements
#define KRANK  103753u   // (DETTOT-1)/2, 0-based median rank

#define SXS 144          // sX row stride (floats)
#define CR  12           // sX chunk rows (46 = 12+12+12+10)

#define CAP  32768       // captured-value list capacity per m (expected ~16K)

// db8 reconstruction filters (pre-derived; dec filters are reversed versions,
// and the reference's conv reduces to: ca[j] = sum_k xe[2j+k]*rec_lo[k])
__device__ __constant__ float RLO[16] = {
    0.05441584224308161f,  0.3128715909144659f,   0.6756307362980128f,
    0.5853546836548691f,  -0.015829105256023893f, -0.2840155429624281f,
    0.00047248457399797254f, 0.128747426620186f,  -0.01736930100202211f,
   -0.04408825393106472f,  0.013981027917015516f,  0.008746094047015655f,
   -0.00487035299301066f, -0.0003917403729959771f, 0.0006754494059985568f,
   -0.00011747678400228192f};
__device__ __constant__ float RHI[16] = {
   -0.00011747678400228192f, -0.0006754494059985568f, -0.0003917403729959771f,
    0.00487035299301066f,     0.008746094047015655f,  -0.013981027917015516f,
   -0.04408825393106472f,     0.01736930100202211f,    0.128747426620186f,
   -0.00047248457399797254f, -0.2840155429624281f,     0.015829105256023893f,
    0.5853546836548691f,     -0.6756307362980128f,     0.3128715909144659f,
   -0.05441584224308161f};

// Symmetric reflection of padded index q into [0, N)
__device__ __forceinline__ int refl(int q, int N) {
    if (q < 0)  return -q - 1;
    if (q >= N) return 2 * N - 1 - q;
    return q;
}

__device__ __forceinline__ float softthr(float v, float thr) {
    float a = fabsf(v) - thr;
    return a > 0.f ? copysignf(a, v) : 0.f;
}

// -------- zero-init for histogram region (no hipMemsetAsync in capture) --------
__global__ __launch_bounds__(256) void k_zero(unsigned* __restrict__ p, int n) {
    int i = blockIdx.x * 256 + threadIdx.x;
    if (i < n) p[i] = 0u;
}

// ---------------- Fused forward: row DWT + column DWT ----------------
// (round-2 exact version: 162 us, LDS 30720, occupancy ~54%)
__global__ __launch_bounds__(256) void k_fwd(const float* __restrict__ x,
                                             float* __restrict__ ll,
                                             float* __restrict__ det) {
    __shared__ float sX[CR * SXS];                 // 6.75 KB, reused 4x
    __shared__ float sLO[46 * 64], sHI[46 * 64];   // 11.5 KB each
    const int m   = blockIdx.x;                    // channels adjacent in dispatch
    const int jw0 = blockIdx.y * 64;               // 5 tiles
    const int jh0 = blockIdx.z * 16;               // 17 tiles
    const int b = m / 3, c = m - 3 * (m / 3);
    const int tid = threadIdx.x;
    const int prow0 = 2 * jh0 - 14, pcol0 = 2 * jw0 - 14;
    // chunked: stage CR padded-rows, row-DWT them, repeat (sX reused)
    for (int r0 = 0; r0 < 46; r0 += CR) {
        const int nr = (46 - r0) < CR ? (46 - r0) : CR;
        for (int l = tid; l < nr * 142; l += 256) {
            int rr = l / 142, cl = l - rr * 142;
            int h = refl(prow0 + r0 + rr, H_);
            int w = refl(pcol0 + cl, W_);
            sX[rr * SXS + cl] = x[((size_t)(b * H_ + h) * W_ + w) * C_ + c];
        }
        __syncthreads();
        for (int l = tid; l < nr * 64; l += 256) {
            int rr = l >> 6, j = l & 63;
            const float* px = &sX[rr * SXS + 2 * j];
            float al = 0.f, ah = 0.f;
#pragma unroll
            for (int k = 0; k < 16; ++k) {
                al = fmaf(px[k], RLO[k], al);
                ah = fmaf(px[k], RHI[k], ah);
            }
            sLO[(r0 + rr) * 64 + j] = al;
            sHI[(r0 + rr) * 64 + j] = ah;
        }
        __syncthreads();                           // sX reused next chunk
    }
    // column DWT: thread computes 4 consecutive jh (dy = 4*tg+d) at col tx,
    // loading the shared 22-row window once into registers.
    const int tx = tid & 63, tg = tid >> 6;
    const int jw = jw0 + tx;
    if (jw >= NW_) return;
    float vl[22], vh[22];
#pragma unroll
    for (int s = 0; s < 22; ++s) {
        int row = 8 * tg + s;                      // <= 45
        vl[s] = sLO[row * 64 + tx];
        vh[s] = sHI[row * 64 + tx];
    }
    float* llp = ll + (size_t)m * DETPER;
    float* dp  = det + (size_t)m * DETSTRIDE;
#pragma unroll
    for (int d = 0; d < 4; ++d) {
        int jh = jh0 + 4 * tg + d;
        if (jh >= NH_) continue;
        float a0 = 0.f, a1 = 0.f, a2 = 0.f, a3 = 0.f;
#pragma unroll
        for (int k = 0; k < 16; ++k) {
            float fl = vl[2 * d + k], fh = vh[2 * d + k];
            a0 = fmaf(fl, RLO[k], a0);
            a1 = fmaf(fl, RHI[k], a1);
            a2 = fmaf(fh, RLO[k], a2);
            a3 = fmaf(fh, RHI[k], a3);
        }
        size_t o = (size_t)jh * NW_ + jw;
        llp[o] = a0;                               // LL
        dp[o] = a1;                                // LH
        dp[DETPER + o] = a2;                       // HL
        dp[2 * DETPER + o] = a3;                   // HH
    }
}

// ---------------- Median: 3-pass radix histogram refinement over det ----------
__global__ __launch_bounds__(256) void k_hist1(const float* __restrict__ det,
                                               unsigned* __restrict__ hist) {
    __shared__ unsigned h[2048];
    const int tid = threadIdx.x, m = blockIdx.x;
    for (int i = tid; i < 2048; i += 256) h[i] = 0u;
    __syncthreads();
    const float* dp = det + (size_t)m * DETSTRIDE;
    const float4* dp4 = (const float4*)dp;
    const int stride = gridDim.y * 256;
    for (int v = blockIdx.y * 256 + tid; v < NVEC; v += stride) {
        float4 f = dp4[v];
        atomicAdd(&h[__float_as_uint(fabsf(f.x)) >> 21], 1u);
        atomicAdd(&h[__float_as_uint(fabsf(f.y)) >> 21], 1u);
        atomicAdd(&h[__float_as_uint(fabsf(f.z)) >> 21], 1u);
        atomicAdd(&h[__float_as_uint(fabsf(f.w)) >> 21], 1u);
    }
    if (blockIdx.y == 0 && tid < DETTOT - 4 * NVEC) {
        unsigned u = __float_as_uint(fabsf(dp[4 * NVEC + tid]));
        atomicAdd(&h[u >> 21], 1u);
    }
    __syncthreads();
    for (int i = tid; i < 2048; i += 256)
        if (h[i]) atomicAdd(&hist[m * 2048 + i], h[i]);
}

// hist2: scan det, histogram mid-11 bits of elements matching selBin1, and
// capture their bit-patterns into a per-m global list. Wave-aggregated
// reservation: one atomicAdd per wave via ballot/popc (round-3's per-element
// LDS atomic serialized ~64x worse).
__global__ __launch_bounds__(256) void k_hist2(const float* __restrict__ det,
                                               const int* __restrict__ selBin1,
                                               unsigned* __restrict__ hist,
                                               unsigned* __restrict__ cnt,
                                               unsigned* __restrict__ list,
                                               int docap) {
    __shared__ unsigned h[2048];
    const int tid = threadIdx.x, m = blockIdx.x;
    const unsigned target = (unsigned)selBin1[m];
    for (int i = tid; i < 2048; i += 256) h[i] = 0u;
    __syncthreads();
    const float* dp = det + (size_t)m * DETSTRIDE;
    const float4* dp4 = (const float4*)dp;
    const int stride = gridDim.y * 256;
    unsigned* const lst = list + (size_t)m * CAP;
    const unsigned lane = tid & 63;
    auto take = [&](unsigned u) {
        bool pred = ((u >> 21) == target);
        if (pred) atomicAdd(&h[(u >> 10) & 0x7FFu], 1u);
        if (docap) {
            unsigned long long mask = __ballot(pred);
            if (pred) {
                unsigned off = (unsigned)__popcll(mask & ((1ull << lane) - 1ull));
                int leader = __ffsll((unsigned long long)mask) - 1;
                unsigned base = 0u;
                if ((int)lane == leader) base = atomicAdd(&cnt[m], (unsigned)__popcll(mask));
                base = (unsigned)__shfl((int)base, leader, 64);
                unsigned p = base + off;
                if (p < CAP) lst[p] = u;
            }
        }
    };
    for (int v = blockIdx.y * 256 + tid; v < NVEC; v += stride) {
        float4 f = dp4[v];
        take(__float_as_uint(fabsf(f.x)));
        take(__float_as_uint(fabsf(f.y)));
        take(__float_as_uint(fabsf(f.z)));
        take(__float_as_uint(fabsf(f.w)));
    }
    if (blockIdx.y == 0 && tid < DETTOT - 4 * NVEC)
        take(__float_as_uint(fabsf(dp[4 * NVEC + tid])));
    __syncthreads();
    for (int i = tid; i < 2048; i += 256)
        if (h[i]) atomicAdd(&hist[m * 2048 + i], h[i]);
}

// hist3: fast path reads the captured list (~16K entries/m) instead of det;
// exact full-scan fallback if capture overflowed or was disabled.
__global__ __launch_bounds__(256) void k_hist3(const float* __restrict__ det,
                                               const int* __restrict__ selBin1,
                                               const int* __restrict__ selBin2,
                                               const unsigned* __restrict__ cnt,
                                               const unsigned* __restrict__ list,
                                               int docap,
                                               unsigned* __restrict__ hist) {
    __shared__ unsigned h[1024];
    const int tid = threadIdx.x, m = blockIdx.x;
    for (int i = tid; i < 1024; i += 256) h[i] = 0u;
    __syncthreads();
    const unsigned n = cnt[m];
    const bool fast = docap && (n <= CAP);
    if (fast) {
        const unsigned b2 = (unsigned)selBin2[m];
        const unsigned* lst = list + (size_t)m * CAP;
        const int stride = gridDim.y * 256;
        for (unsigned i = blockIdx.y * 256 + tid; i < n; i += stride) {
            unsigned u = lst[i];
            if (((u >> 10) & 0x7FFu) == b2) atomicAdd(&h[u & 0x3FFu], 1u);
        }
    } else {
        const unsigned target = ((unsigned)selBin1[m] << 11) | (unsigned)selBin2[m];
        const float* dp = det + (size_t)m * DETSTRIDE;
        const float4* dp4 = (const float4*)dp;
        const int stride = gridDim.y * 256;
        for (int v = blockIdx.y * 256 + tid; v < NVEC; v += stride) {
            float4 f = dp4[v];
            unsigned a = __float_as_uint(fabsf(f.x));
            unsigned b = __float_as_uint(fabsf(f.y));
            unsigned c = __float_as_uint(fabsf(f.z));
            unsigned d = __float_as_uint(fabsf(f.w));
            if ((a >> 10) == target) atomicAdd(&h[a & 0x3FFu], 1u);
            if ((b >> 10) == target) atomicAdd(&h[b & 0x3FFu], 1u);
            if ((c >> 10) == target) atomicAdd(&h[c & 0x3FFu], 1u);
            if ((d >> 10) == target) atomicAdd(&h[d & 0x3FFu], 1u);
        }
        if (blockIdx.y == 0 && tid < DETTOT - 4 * NVEC) {
            unsigned u = __float_as_uint(fabsf(dp[4 * NVEC + tid]));
            if ((u >> 10) == target) atomicAdd(&h[u & 0x3FFu], 1u);
        }
    }
    __syncthreads();
    for (int i = tid; i < 1024; i += 256)
        if (h[i]) atomicAdd(&hist[m * 1024 + i], h[i]);
}

// Cooperative select: find bin of LDS histogram (nb multiple of 256) containing `rank`
__device__ int histSelect(unsigned* hist, int nb, unsigned rank, unsigned* rem) {
    __shared__ unsigned ps[256];
    __shared__ int s_bin;
    __shared__ unsigned s_rem;
    const int tid = threadIdx.x;
    if (tid == 0) { s_bin = 0; s_rem = 0; }      // deterministic fallback
    const int per = nb >> 8;
    unsigned s = 0;
    for (int i = 0; i < per; ++i) s += hist[tid * per + i];
    ps[tid] = s;
    __syncthreads();
    for (int off = 1; off < 256; off <<= 1) {
        unsigned v = ps[tid];
        unsigned add = (tid >= off) ? ps[tid - off] : 0u;
        __syncthreads();
        ps[tid] = v + add;
        __syncthreads();
    }
    unsigned incl = ps[tid], excl = incl - s;
    if (rank >= excl && rank < incl) {
        unsigned cum = excl;
        for (int i = 0; i < per; ++i) {
            unsigned c = hist[tid * per + i];
            if (cum + c > rank) { s_bin = tid * per + i; s_rem = rank - cum; break; }
            cum += c;
        }
    }
    __syncthreads();
    int rbin = s_bin;
    unsigned rr = s_rem;
    __syncthreads();   // protect shared reuse across calls
    *rem = rr;
    return rbin;
}

__global__ __launch_bounds__(256) void k_sel2048(const unsigned* __restrict__ hist,
                                                 const unsigned* __restrict__ rankIn, // null => KRANK
                                                 int* __restrict__ selBin,
                                                 unsigned* __restrict__ rankOut) {
    __shared__ unsigned h[2048];
    const int m = blockIdx.x, tid = threadIdx.x;
    for (int i = tid; i < 2048; i += 256) h[i] = hist[m * 2048 + i];
    __syncthreads();
    unsigned rank = rankIn ? rankIn[m] : KRANK;
    unsigned rem;
    int bin = histSelect(h, 2048, rank, &rem);
    if (tid == 0) { selBin[m] = bin; rankOut[m] = rem; }
}

__global__ __launch_bounds__(256) void k_sel3(const unsigned* __restrict__ hist,
                                              const unsigned* __restrict__ rankIn,
                                              const int* __restrict__ selBin1,
                                              const int* __restrict__ selBin2,
                                              float* __restrict__ tval) {
    __shared__ unsigned h[1024];
    const int m = blockIdx.x, tid = threadIdx.x;
    for (int i = tid; i < 1024; i += 256) h[i] = hist[m * 1024 + i];
    __syncthreads();
    unsigned rem;
    int low = histSelect(h, 1024, rankIn[m], &rem);
    if (tid == 0) {
        unsigned bits = ((unsigned)selBin1[m] << 21) | ((unsigned)selBin2[m] << 10) | (unsigned)low;
        double med = (double)__uint_as_float(bits);
        // t = median/0.6745 * sqrt(2*ln(512*512))
        tval[m] = (float)(med / 0.6745 * 4.995327667046959);
    }
}

// ---------------- Fused inverse: soft-threshold + column IDWT + row IDWT ------
// v3: LDS-pipe reduction. Col-IDWT items = (row-pair s, col-quad q): both output
// parities (rows 2s, 2s+1) share the same 8 source rows, so 32 ds_read_b128
// produce 16 outputs (vs round-0's 32 scalar reads per output — 16x fewer LDS
// instructions). Row-IDWT = balanced b128 form (8 outputs/thread, arithmetic
// identical to round-0, verified in round-1). Staging unchanged.
__global__ __launch_bounds__(256) void k_inv(const float* __restrict__ ll,
                                             const float* __restrict__ det,
                                             const float* __restrict__ tval,
                                             float* __restrict__ out) {
    __shared__ float sLL[23 * 40], sLH[23 * 40], sHL[23 * 40], sHH[23 * 40];
    __shared__ float sRL[32 * 40], sRH[32 * 40];
    const int m  = blockIdx.x;                   // channels adjacent in dispatch
    const int w0 = blockIdx.y * 64;              // 8 tiles
    const int t0 = blockIdx.z * 32;              // 16 tiles
    const int b = m / 3, c = m - 3 * (m / 3);
    const int tid = threadIdx.x;
    const float thr = tval[m];
    const int jW0 = w0 >> 1, s0 = t0 >> 1;
    const float* llp = ll + (size_t)m * DETPER;
    const float* dp  = det + (size_t)m * DETSTRIDE;
    for (int l = tid; l < 23 * 39; l += 256) {
        int rr = l / 39, cc = l - rr * 39;
        size_t o = (size_t)(s0 + rr) * NW_ + (jW0 + cc);
        int li = rr * 40 + cc;
        sLL[li] = llp[o];
        sLH[li] = softthr(dp[o], thr);
        sHL[li] = softthr(dp[DETPER + o], thr);
        sHH[li] = softthr(dp[2 * DETPER + o], thr);
    }
    __syncthreads();
    // column IDWT: item (s in [0,16), q in [0,10)) -> output rows 2s,2s+1,
    // cols 4q..4q+3. Source rows s..s+7 (<=22), col quad 4q (<=36; col 39 of
    // sLL/... is uninitialized but its results land in sRL/sRH col 39, which
    // the row-IDWT never reads).
    for (int l = tid; l < 160; l += 256) {
        int s = l / 10, q = l - 10 * (l / 10);
        float4 aL0 = make_float4(0.f, 0.f, 0.f, 0.f), aL1 = aL0, aH0 = aL0, aH1 = aL0;
#pragma unroll
        for (int a = 0; a < 8; ++a) {
            int li = (s + 7 - a) * 40 + 4 * q;
            float4 vLL = *(const float4*)&sLL[li];
            float4 vLH = *(const float4*)&sLH[li];
            float4 vHL = *(const float4*)&sHL[li];
            float4 vHH = *(const float4*)&sHH[li];
            float w00 = RLO[2 * a],     h00 = RHI[2 * a];       // parity r=0
            float w01 = RLO[2 * a + 1], h01 = RHI[2 * a + 1];   // parity r=1
            aL0.x = fmaf(vLL.x, w00, fmaf(vLH.x, h00, aL0.x));
            aL0.y = fmaf(vLL.y, w00, fmaf(vLH.y, h00, aL0.y));
            aL0.z = fmaf(vLL.z, w00, fmaf(vLH.z, h00, aL0.z));
            aL0.w = fmaf(vLL.w, w00, fmaf(vLH.w, h00, aL0.w));
            aL1.x = fmaf(vLL.x, w01, fmaf(vLH.x, h01, aL1.x));
            aL1.y = fmaf(vLL.y, w01, fmaf(vLH.y, h01, aL1.y));
            aL1.z = fmaf(vLL.z, w01, fmaf(vLH.z, h01, aL1.z));
            aL1.w = fmaf(vLL.w, w01, fmaf(vLH.w, h01, aL1.w));
            aH0.x = fmaf(vHL.x, w00, fmaf(vHH.x, h00, aH0.x));
            aH0.y = fmaf(vHL.y, w00, fmaf(vHH.y, h00, aH0.y));
            aH0.z = fmaf(vHL.z, w00, fmaf(vHH.z, h00, aH0.z));
            aH0.w = fmaf(vHL.w, w00, fmaf(vHH.w, h00, aH0.w));
            aH1.x = fmaf(vHL.x, w01, fmaf(vHH.x, h01, aH1.x));
            aH1.y = fmaf(vHL.y, w01, fmaf(vHH.y, h01, aH1.y));
            aH1.z = fmaf(vHL.z, w01, fmaf(vHH.z, h01, aH1.z));
            aH1.w = fmaf(vHL.w, w01, fmaf(vHH.w, h01, aH1.w));
        }
        *(float4*)&sRL[(2 * s) * 40 + 4 * q]     = aL0;
        *(float4*)&sRL[(2 * s + 1) * 40 + 4 * q] = aL1;
        *(float4*)&sRH[(2 * s) * 40 + 4 * q]     = aH0;
        *(float4*)&sRH[(2 * s + 1) * 40 + 4 * q] = aH1;
    }
    __syncthreads();
    // row IDWT + NHWC store: thread (tr = tid>>3, jg = tid&7) produces the 8
    // outputs wloc = 8jg..8jg+7 from words [4jg, 4jg+10] of sRL/sRH (3 b128 each).
    {
        const int tr = tid >> 3, jg = tid & 7;
        const float4* pl = (const float4*)&sRL[tr * 40 + 4 * jg];  // 16B aligned
        const float4* ph = (const float4*)&sRH[tr * 40 + 4 * jg];
        float4 L0 = pl[0], L1 = pl[1], L2 = pl[2];
        float4 K0 = ph[0], K1 = ph[1], K2 = ph[2];
        float rl[12] = {L0.x,L0.y,L0.z,L0.w, L1.x,L1.y,L1.z,L1.w, L2.x,L2.y,L2.z,L2.w};
        float rh[12] = {K0.x,K0.y,K0.z,K0.w, K1.x,K1.y,K1.z,K1.w, K2.x,K2.y,K2.z,K2.w};
        size_t obase = ((size_t)(b * H_ + (t0 + tr)) * W_ + (w0 + 8 * jg)) * C_ + c;
#pragma unroll
        for (int u = 0; u < 4; ++u) {
#pragma unroll
            for (int r = 0; r < 2; ++r) {
                float acc = 0.f;
#pragma unroll
                for (int a = 0; a < 8; ++a) {
                    int sdx = u + 7 - a;         // in [u, u+7] subset of [0,10]
                    acc = fmaf(rl[sdx], RLO[2 * a + r], fmaf(rh[sdx], RHI[2 * a + r], acc));
                }
                out[obase + (size_t)(2 * u + r) * C_] = acc;
            }
        }
    }
}

extern "C" void kernel_launch(void* const* d_in, const int* in_sizes, int n_in,
                              void* d_out, int out_size, void* d_ws, size_t ws_size,
                              hipStream_t stream) {
    const float* x = (const float*)d_in[0];
    float* out = (float*)d_out;

    char* ws = (char*)d_ws;
    float* ll  = (float*)ws; ws += (size_t)M_ * DETPER * 4;     // 26.56 MB
    float* det = (float*)ws; ws += (size_t)M_ * DETSTRIDE * 4;  // 79.68 MB  [m][{lh,hl,hh}][DETPER]
    unsigned* hist1 = (unsigned*)ws; ws += (size_t)M_ * 2048 * 4;
    unsigned* hist2 = (unsigned*)ws; ws += (size_t)M_ * 2048 * 4;
    unsigned* hist3 = (unsigned*)ws; ws += (size_t)M_ * 1024 * 4;
    unsigned* cnt   = (unsigned*)ws;   ws += M_ * 4;            // contiguous with hists (zeroed)
    int*      selBin1 = (int*)ws;      ws += M_ * 4;
    int*      selBin2 = (int*)ws;      ws += M_ * 4;
    unsigned* rank1   = (unsigned*)ws; ws += M_ * 4;
    unsigned* rank2   = (unsigned*)ws; ws += M_ * 4;
    float*    tval    = (float*)ws;    ws += M_ * 4;
    unsigned* list    = (unsigned*)ws; ws += (size_t)M_ * CAP * 4;  // 12.58 MB
    // total ws usage: ~120.9 MB
    const int docap = (ws_size >= (size_t)((char*)(list + (size_t)M_ * CAP) - (char*)d_ws)) ? 1 : 0;

    const int histWords = M_ * (2048 + 2048 + 1024) + M_;       // hists + cnt
    k_zero   <<<dim3((histWords + 255) / 256), 256, 0, stream>>>(hist1, histWords);
    k_fwd    <<<dim3(M_, 5, 17),  256, 0, stream>>>(x, ll, det);
    k_hist1  <<<dim3(M_, 16),     256, 0, stream>>>(det, hist1);
    k_sel2048<<<dim3(M_),         256, 0, stream>>>(hist1, nullptr, selBin1, rank1);
    k_hist2  <<<dim3(M_, 16),     256, 0, stream>>>(det, selBin1, hist2, cnt, list, docap);
    k_sel2048<<<dim3(M_),         256, 0, stream>>>(hist2, rank1, selBin2, rank2);
    k_hist3  <<<dim3(M_, 16),     256, 0, stream>>>(det, selBin1, selBin2, cnt, list, docap, hist3);
    k_sel3   <<<dim3(M_),         256, 0, stream>>>(hist3, rank2, selBin1, selBin2, tval);
    k_inv    <<<dim3(M_, 8, 16),  256, 0, stream>>>(ll, det, tval, out);
}

// Round 5
// 471.525 us; speedup vs baseline: 3.0447x; 3.0447x over previous
//
#include <hip/hip_runtime.h>
#include <math.h>

// Problem constants
#define B_   32
#define H_   512
#define W_   512
#define C_   3
#define M_   96          // B_*C_
#define NW_  263         // floor((512+15)/2)
#define NH_  263
#define DETPER 69169     // 263*263
#define DETTOT 207507    // 3*DETPER
#define DETSTRIDE 207508 // padded to multiple of 4 for float4 alignment
#define NVEC 51876       // DETTOT/4 (floor); tail = 3 elements
#define KRANK  103753u   // (DETTOT-1)/2, 0-based median rank

#define SXS 144          // sX row stride (floats)
#define CR  12           // sX chunk rows (46 = 12+12+12+10)

#define NBY   16         // hist kernels gridDim.y
#define SLICE 2048       // per-(m,by) capture slice (expected ~1000 entries)

// db8 reconstruction filters (pre-derived; dec filters are reversed versions,
// and the reference's conv reduces to: ca[j] = sum_k xe[2j+k]*rec_lo[k])
__device__ __constant__ float RLO[16] = {
    0.05441584224308161f,  0.3128715909144659f,   0.6756307362980128f,
    0.5853546836548691f,  -0.015829105256023893f, -0.2840155429624281f,
    0.00047248457399797254f, 0.128747426620186f,  -0.01736930100202211f,
   -0.04408825393106472f,  0.013981027917015516f,  0.008746094047015655f,
   -0.00487035299301066f, -0.0003917403729959771f, 0.0006754494059985568f,
   -0.00011747678400228192f};
__device__ __constant__ float RHI[16] = {
   -0.00011747678400228192f, -0.0006754494059985568f, -0.0003917403729959771f,
    0.00487035299301066f,     0.008746094047015655f,  -0.013981027917015516f,
   -0.04408825393106472f,     0.01736930100202211f,    0.128747426620186f,
   -0.00047248457399797254f, -0.2840155429624281f,     0.015829105256023893f,
    0.5853546836548691f,     -0.6756307362980128f,     0.3128715909144659f,
   -0.05441584224308161f};

// Symmetric reflection of padded index q into [0, N)
__device__ __forceinline__ int refl(int q, int N) {
    if (q < 0)  return -q - 1;
    if (q >= N) return 2 * N - 1 - q;
    return q;
}

__device__ __forceinline__ float softthr(float v, float thr) {
    float a = fabsf(v) - thr;
    return a > 0.f ? copysignf(a, v) : 0.f;
}

// -------- zero-init for histogram region (no hipMemsetAsync in capture) --------
__global__ __launch_bounds__(256) void k_zero(unsigned* __restrict__ p, int n) {
    int i = blockIdx.x * 256 + threadIdx.x;
    if (i < n) p[i] = 0u;
}

// ---------------- Fused forward: row DWT + column DWT ----------------
// (round-2 exact version: 162 us, LDS 30720, occupancy ~54%)
__global__ __launch_bounds__(256) void k_fwd(const float* __restrict__ x,
                                             float* __restrict__ ll,
                                             float* __restrict__ det) {
    __shared__ float sX[CR * SXS];                 // 6.75 KB, reused 4x
    __shared__ float sLO[46 * 64], sHI[46 * 64];   // 11.5 KB each
    const int m   = blockIdx.x;                    // channels adjacent in dispatch
    const int jw0 = blockIdx.y * 64;               // 5 tiles
    const int jh0 = blockIdx.z * 16;               // 17 tiles
    const int b = m / 3, c = m - 3 * (m / 3);
    const int tid = threadIdx.x;
    const int prow0 = 2 * jh0 - 14, pcol0 = 2 * jw0 - 14;
    // chunked: stage CR padded-rows, row-DWT them, repeat (sX reused)
    for (int r0 = 0; r0 < 46; r0 += CR) {
        const int nr = (46 - r0) < CR ? (46 - r0) : CR;
        for (int l = tid; l < nr * 142; l += 256) {
            int rr = l / 142, cl = l - rr * 142;
            int h = refl(prow0 + r0 + rr, H_);
            int w = refl(pcol0 + cl, W_);
            sX[rr * SXS + cl] = x[((size_t)(b * H_ + h) * W_ + w) * C_ + c];
        }
        __syncthreads();
        for (int l = tid; l < nr * 64; l += 256) {
            int rr = l >> 6, j = l & 63;
            const float* px = &sX[rr * SXS + 2 * j];
            float al = 0.f, ah = 0.f;
#pragma unroll
            for (int k = 0; k < 16; ++k) {
                al = fmaf(px[k], RLO[k], al);
                ah = fmaf(px[k], RHI[k], ah);
            }
            sLO[(r0 + rr) * 64 + j] = al;
            sHI[(r0 + rr) * 64 + j] = ah;
        }
        __syncthreads();                           // sX reused next chunk
    }
    // column DWT: thread computes 4 consecutive jh (dy = 4*tg+d) at col tx,
    // loading the shared 22-row window once into registers.
    const int tx = tid & 63, tg = tid >> 6;
    const int jw = jw0 + tx;
    if (jw >= NW_) return;
    float vl[22], vh[22];
#pragma unroll
    for (int s = 0; s < 22; ++s) {
        int row = 8 * tg + s;                      // <= 45
        vl[s] = sLO[row * 64 + tx];
        vh[s] = sHI[row * 64 + tx];
    }
    float* llp = ll + (size_t)m * DETPER;
    float* dp  = det + (size_t)m * DETSTRIDE;
#pragma unroll
    for (int d = 0; d < 4; ++d) {
        int jh = jh0 + 4 * tg + d;
        if (jh >= NH_) continue;
        float a0 = 0.f, a1 = 0.f, a2 = 0.f, a3 = 0.f;
#pragma unroll
        for (int k = 0; k < 16; ++k) {
            float fl = vl[2 * d + k], fh = vh[2 * d + k];
            a0 = fmaf(fl, RLO[k], a0);
            a1 = fmaf(fl, RHI[k], a1);
            a2 = fmaf(fh, RLO[k], a2);
            a3 = fmaf(fh, RHI[k], a3);
        }
        size_t o = (size_t)jh * NW_ + jw;
        llp[o] = a0;                               // LL
        dp[o] = a1;                                // LH
        dp[DETPER + o] = a2;                       // HL
        dp[2 * DETPER + o] = a3;                   // HH
    }
}

// ---------------- Median: 3-pass radix histogram refinement over det ----------
__global__ __launch_bounds__(256) void k_hist1(const float* __restrict__ det,
                                               unsigned* __restrict__ hist) {
    __shared__ unsigned h[2048];
    const int tid = threadIdx.x, m = blockIdx.x;
    for (int i = tid; i < 2048; i += 256) h[i] = 0u;
    __syncthreads();
    const float* dp = det + (size_t)m * DETSTRIDE;
    const float4* dp4 = (const float4*)dp;
    const int stride = gridDim.y * 256;
    for (int v = blockIdx.y * 256 + tid; v < NVEC; v += stride) {
        float4 f = dp4[v];
        atomicAdd(&h[__float_as_uint(fabsf(f.x)) >> 21], 1u);
        atomicAdd(&h[__float_as_uint(fabsf(f.y)) >> 21], 1u);
        atomicAdd(&h[__float_as_uint(fabsf(f.z)) >> 21], 1u);
        atomicAdd(&h[__float_as_uint(fabsf(f.w)) >> 21], 1u);
    }
    if (blockIdx.y == 0 && tid < DETTOT - 4 * NVEC) {
        unsigned u = __float_as_uint(fabsf(dp[4 * NVEC + tid]));
        atomicAdd(&h[u >> 21], 1u);
    }
    __syncthreads();
    for (int i = tid; i < 2048; i += 256)
        if (h[i]) atomicAdd(&hist[m * 2048 + i], h[i]);
}

// hist2: scan det, histogram mid-11 bits of elements matching selBin1, and
// capture matching bit-patterns. v3 of capture: per-(m,by) PRIVATE slice of
// the list + block-local LDS counter with wave-aggregated reservation.
// Zero cross-block communication (round 4's single global counter serialized
// at ~300ns/atomic cross-XCD = 979 us; round 3's per-element LDS counter
// over-serialized 64x).
__global__ __launch_bounds__(256) void k_hist2(const float* __restrict__ det,
                                               const int* __restrict__ selBin1,
                                               unsigned* __restrict__ hist,
                                               unsigned* __restrict__ cnt,
                                               unsigned* __restrict__ list,
                                               int docap) {
    __shared__ unsigned h[2048];
    __shared__ unsigned ccnt;
    const int tid = threadIdx.x, m = blockIdx.x, by = blockIdx.y;
    const unsigned target = (unsigned)selBin1[m];
    for (int i = tid; i < 2048; i += 256) h[i] = 0u;
    if (tid == 0) ccnt = 0u;
    __syncthreads();
    const float* dp = det + (size_t)m * DETSTRIDE;
    const float4* dp4 = (const float4*)dp;
    const int stride = gridDim.y * 256;
    unsigned* const lst = list + ((size_t)m * NBY + by) * SLICE;
    const unsigned lane = tid & 63;
    auto take = [&](unsigned u) {
        bool pred = ((u >> 21) == target);
        if (pred) atomicAdd(&h[(u >> 10) & 0x7FFu], 1u);
        if (docap) {
            unsigned long long mask = __ballot(pred);
            if (pred) {
                unsigned off = (unsigned)__popcll(mask & ((1ull << lane) - 1ull));
                int leader = __ffsll((unsigned long long)mask) - 1;
                unsigned base = 0u;
                if ((int)lane == leader)
                    base = atomicAdd(&ccnt, (unsigned)__popcll(mask));  // LDS, block-local
                base = (unsigned)__shfl((int)base, leader, 64);
                unsigned p = base + off;
                if (p < SLICE) lst[p] = u;
            }
        }
    };
    for (int v = by * 256 + tid; v < NVEC; v += stride) {
        float4 f = dp4[v];
        take(__float_as_uint(fabsf(f.x)));
        take(__float_as_uint(fabsf(f.y)));
        take(__float_as_uint(fabsf(f.z)));
        take(__float_as_uint(fabsf(f.w)));
    }
    if (by == 0 && tid < DETTOT - 4 * NVEC)
        take(__float_as_uint(fabsf(dp[4 * NVEC + tid])));
    __syncthreads();
    if (docap && tid == 0) cnt[m * NBY + by] = ccnt;   // uncapped; hist3 validates
    for (int i = tid; i < 2048; i += 256)
        if (h[i]) atomicAdd(&hist[m * 2048 + i], h[i]);
}

// hist3: fast path — block (m,by) reads its own captured slice (~1K entries);
// uniform fallback to full 80MB scan if any slice overflowed or capture off.
__global__ __launch_bounds__(256) void k_hist3(const float* __restrict__ det,
                                               const int* __restrict__ selBin1,
                                               const int* __restrict__ selBin2,
                                               const unsigned* __restrict__ cnt,
                                               const unsigned* __restrict__ list,
                                               int docap,
                                               unsigned* __restrict__ hist) {
    __shared__ unsigned h[1024];
    const int tid = threadIdx.x, m = blockIdx.x, by = blockIdx.y;
    for (int i = tid; i < 1024; i += 256) h[i] = 0u;
    __syncthreads();
    bool fast = (docap != 0);
    if (fast) {
#pragma unroll
        for (int i = 0; i < NBY; ++i)
            if (cnt[m * NBY + i] > SLICE) fast = false;   // uniform across m's blocks
    }
    if (fast) {
        const unsigned b2 = (unsigned)selBin2[m];
        const unsigned n = cnt[m * NBY + by];
        const unsigned* lst = list + ((size_t)m * NBY + by) * SLICE;
        for (unsigned i = tid; i < n; i += 256) {
            unsigned u = lst[i];
            if (((u >> 10) & 0x7FFu) == b2) atomicAdd(&h[u & 0x3FFu], 1u);
        }
    } else {
        const unsigned target = ((unsigned)selBin1[m] << 11) | (unsigned)selBin2[m];
        const float* dp = det + (size_t)m * DETSTRIDE;
        const float4* dp4 = (const float4*)dp;
        const int stride = gridDim.y * 256;
        for (int v = by * 256 + tid; v < NVEC; v += stride) {
            float4 f = dp4[v];
            unsigned a = __float_as_uint(fabsf(f.x));
            unsigned b = __float_as_uint(fabsf(f.y));
            unsigned c = __float_as_uint(fabsf(f.z));
            unsigned d = __float_as_uint(fabsf(f.w));
            if ((a >> 10) == target) atomicAdd(&h[a & 0x3FFu], 1u);
            if ((b >> 10) == target) atomicAdd(&h[b & 0x3FFu], 1u);
            if ((c >> 10) == target) atomicAdd(&h[c & 0x3FFu], 1u);
            if ((d >> 10) == target) atomicAdd(&h[d & 0x3FFu], 1u);
        }
        if (by == 0 && tid < DETTOT - 4 * NVEC) {
            unsigned u = __float_as_uint(fabsf(dp[4 * NVEC + tid]));
            if ((u >> 10) == target) atomicAdd(&h[u & 0x3FFu], 1u);
        }
    }
    __syncthreads();
    for (int i = tid; i < 1024; i += 256)
        if (h[i]) atomicAdd(&hist[m * 1024 + i], h[i]);
}

// Cooperative select: find bin of LDS histogram (nb multiple of 256) containing `rank`
__device__ int histSelect(unsigned* hist, int nb, unsigned rank, unsigned* rem) {
    __shared__ unsigned ps[256];
    __shared__ int s_bin;
    __shared__ unsigned s_rem;
    const int tid = threadIdx.x;
    if (tid == 0) { s_bin = 0; s_rem = 0; }      // deterministic fallback
    const int per = nb >> 8;
    unsigned s = 0;
    for (int i = 0; i < per; ++i) s += hist[tid * per + i];
    ps[tid] = s;
    __syncthreads();
    for (int off = 1; off < 256; off <<= 1) {
        unsigned v = ps[tid];
        unsigned add = (tid >= off) ? ps[tid - off] : 0u;
        __syncthreads();
        ps[tid] = v + add;
        __syncthreads();
    }
    unsigned incl = ps[tid], excl = incl - s;
    if (rank >= excl && rank < incl) {
        unsigned cum = excl;
        for (int i = 0; i < per; ++i) {
            unsigned c = hist[tid * per + i];
            if (cum + c > rank) { s_bin = tid * per + i; s_rem = rank - cum; break; }
            cum += c;
        }
    }
    __syncthreads();
    int rbin = s_bin;
    unsigned rr = s_rem;
    __syncthreads();   // protect shared reuse across calls
    *rem = rr;
    return rbin;
}

__global__ __launch_bounds__(256) void k_sel2048(const unsigned* __restrict__ hist,
                                                 const unsigned* __restrict__ rankIn, // null => KRANK
                                                 int* __restrict__ selBin,
                                                 unsigned* __restrict__ rankOut) {
    __shared__ unsigned h[2048];
    const int m = blockIdx.x, tid = threadIdx.x;
    for (int i = tid; i < 2048; i += 256) h[i] = hist[m * 2048 + i];
    __syncthreads();
    unsigned rank = rankIn ? rankIn[m] : KRANK;
    unsigned rem;
    int bin = histSelect(h, 2048, rank, &rem);
    if (tid == 0) { selBin[m] = bin; rankOut[m] = rem; }
}

__global__ __launch_bounds__(256) void k_sel3(const unsigned* __restrict__ hist,
                                              const unsigned* __restrict__ rankIn,
                                              const int* __restrict__ selBin1,
                                              const int* __restrict__ selBin2,
                                              float* __restrict__ tval) {
    __shared__ unsigned h[1024];
    const int m = blockIdx.x, tid = threadIdx.x;
    for (int i = tid; i < 1024; i += 256) h[i] = hist[m * 1024 + i];
    __syncthreads();
    unsigned rem;
    int low = histSelect(h, 1024, rankIn[m], &rem);
    if (tid == 0) {
        unsigned bits = ((unsigned)selBin1[m] << 21) | ((unsigned)selBin2[m] << 10) | (unsigned)low;
        double med = (double)__uint_as_float(bits);
        // t = median/0.6745 * sqrt(2*ln(512*512))
        tval[m] = (float)(med / 0.6745 * 4.995327667046959);
    }
}

// ---------------- Fused inverse: soft-threshold + column IDWT + row IDWT ------
// v3: LDS-pipe reduction. Col-IDWT items = (row-pair s, col-quad q): both output
// parities (rows 2s, 2s+1) share the same 8 source rows, so 32 ds_read_b128
// produce 16 outputs. Row-IDWT = balanced b128 form (8 outputs/thread).
__global__ __launch_bounds__(256) void k_inv(const float* __restrict__ ll,
                                             const float* __restrict__ det,
                                             const float* __restrict__ tval,
                                             float* __restrict__ out) {
    __shared__ float sLL[23 * 40], sLH[23 * 40], sHL[23 * 40], sHH[23 * 40];
    __shared__ float sRL[32 * 40], sRH[32 * 40];
    const int m  = blockIdx.x;                   // channels adjacent in dispatch
    const int w0 = blockIdx.y * 64;              // 8 tiles
    const int t0 = blockIdx.z * 32;              // 16 tiles
    const int b = m / 3, c = m - 3 * (m / 3);
    const int tid = threadIdx.x;
    const float thr = tval[m];
    const int jW0 = w0 >> 1, s0 = t0 >> 1;
    const float* llp = ll + (size_t)m * DETPER;
    const float* dp  = det + (size_t)m * DETSTRIDE;
    for (int l = tid; l < 23 * 39; l += 256) {
        int rr = l / 39, cc = l - rr * 39;
        size_t o = (size_t)(s0 + rr) * NW_ + (jW0 + cc);
        int li = rr * 40 + cc;
        sLL[li] = llp[o];
        sLH[li] = softthr(dp[o], thr);
        sHL[li] = softthr(dp[DETPER + o], thr);
        sHH[li] = softthr(dp[2 * DETPER + o], thr);
    }
    __syncthreads();
    // column IDWT: item (s in [0,16), q in [0,10)) -> output rows 2s,2s+1,
    // cols 4q..4q+3. Source rows s..s+7 (<=22); col 39 never read downstream.
    for (int l = tid; l < 160; l += 256) {
        int s = l / 10, q = l - 10 * (l / 10);
        float4 aL0 = make_float4(0.f, 0.f, 0.f, 0.f), aL1 = aL0, aH0 = aL0, aH1 = aL0;
#pragma unroll
        for (int a = 0; a < 8; ++a) {
            int li = (s + 7 - a) * 40 + 4 * q;
            float4 vLL = *(const float4*)&sLL[li];
            float4 vLH = *(const float4*)&sLH[li];
            float4 vHL = *(const float4*)&sHL[li];
            float4 vHH = *(const float4*)&sHH[li];
            float w00 = RLO[2 * a],     h00 = RHI[2 * a];       // parity r=0
            float w01 = RLO[2 * a + 1], h01 = RHI[2 * a + 1];   // parity r=1
            aL0.x = fmaf(vLL.x, w00, fmaf(vLH.x, h00, aL0.x));
            aL0.y = fmaf(vLL.y, w00, fmaf(vLH.y, h00, aL0.y));
            aL0.z = fmaf(vLL.z, w00, fmaf(vLH.z, h00, aL0.z));
            aL0.w = fmaf(vLL.w, w00, fmaf(vLH.w, h00, aL0.w));
            aL1.x = fmaf(vLL.x, w01, fmaf(vLH.x, h01, aL1.x));
            aL1.y = fmaf(vLL.y, w01, fmaf(vLH.y, h01, aL1.y));
            aL1.z = fmaf(vLL.z, w01, fmaf(vLH.z, h01, aL1.z));
            aL1.w = fmaf(vLL.w, w01, fmaf(vLH.w, h01, aL1.w));
            aH0.x = fmaf(vHL.x, w00, fmaf(vHH.x, h00, aH0.x));
            aH0.y = fmaf(vHL.y, w00, fmaf(vHH.y, h00, aH0.y));
            aH0.z = fmaf(vHL.z, w00, fmaf(vHH.z, h00, aH0.z));
            aH0.w = fmaf(vHL.w, w00, fmaf(vHH.w, h00, aH0.w));
            aH1.x = fmaf(vHL.x, w01, fmaf(vHH.x, h01, aH1.x));
            aH1.y = fmaf(vHL.y, w01, fmaf(vHH.y, h01, aH1.y));
            aH1.z = fmaf(vHL.z, w01, fmaf(vHH.z, h01, aH1.z));
            aH1.w = fmaf(vHL.w, w01, fmaf(vHH.w, h01, aH1.w));
        }
        *(float4*)&sRL[(2 * s) * 40 + 4 * q]     = aL0;
        *(float4*)&sRL[(2 * s + 1) * 40 + 4 * q] = aL1;
        *(float4*)&sRH[(2 * s) * 40 + 4 * q]     = aH0;
        *(float4*)&sRH[(2 * s + 1) * 40 + 4 * q] = aH1;
    }
    __syncthreads();
    // row IDWT + NHWC store: thread (tr = tid>>3, jg = tid&7) produces the 8
    // outputs wloc = 8jg..8jg+7 from words [4jg, 4jg+10] of sRL/sRH (3 b128 each).
    {
        const int tr = tid >> 3, jg = tid & 7;
        const float4* pl = (const float4*)&sRL[tr * 40 + 4 * jg];  // 16B aligned
        const float4* ph = (const float4*)&sRH[tr * 40 + 4 * jg];
        float4 L0 = pl[0], L1 = pl[1], L2 = pl[2];
        float4 K0 = ph[0], K1 = ph[1], K2 = ph[2];
        float rl[12] = {L0.x,L0.y,L0.z,L0.w, L1.x,L1.y,L1.z,L1.w, L2.x,L2.y,L2.z,L2.w};
        float rh[12] = {K0.x,K0.y,K0.z,K0.w, K1.x,K1.y,K1.z,K1.w, K2.x,K2.y,K2.z,K2.w};
        size_t obase = ((size_t)(b * H_ + (t0 + tr)) * W_ + (w0 + 8 * jg)) * C_ + c;
#pragma unroll
        for (int u = 0; u < 4; ++u) {
#pragma unroll
            for (int r = 0; r < 2; ++r) {
                float acc = 0.f;
#pragma unroll
                for (int a = 0; a < 8; ++a) {
                    int sdx = u + 7 - a;         // in [u, u+7] subset of [0,10]
                    acc = fmaf(rl[sdx], RLO[2 * a + r], fmaf(rh[sdx], RHI[2 * a + r], acc));
                }
                out[obase + (size_t)(2 * u + r) * C_] = acc;
            }
        }
    }
}

extern "C" void kernel_launch(void* const* d_in, const int* in_sizes, int n_in,
                              void* d_out, int out_size, void* d_ws, size_t ws_size,
                              hipStream_t stream) {
    const float* x = (const float*)d_in[0];
    float* out = (float*)d_out;

    char* ws = (char*)d_ws;
    float* ll  = (float*)ws; ws += (size_t)M_ * DETPER * 4;     // 26.56 MB
    float* det = (float*)ws; ws += (size_t)M_ * DETSTRIDE * 4;  // 79.68 MB  [m][{lh,hl,hh}][DETPER]
    unsigned* hist1 = (unsigned*)ws; ws += (size_t)M_ * 2048 * 4;
    unsigned* hist2 = (unsigned*)ws; ws += (size_t)M_ * 2048 * 4;
    unsigned* hist3 = (unsigned*)ws; ws += (size_t)M_ * 1024 * 4;
    unsigned* cnt   = (unsigned*)ws;   ws += M_ * NBY * 4;      // per-(m,by) slice counts
    int*      selBin1 = (int*)ws;      ws += M_ * 4;
    int*      selBin2 = (int*)ws;      ws += M_ * 4;
    unsigned* rank1   = (unsigned*)ws; ws += M_ * 4;
    unsigned* rank2   = (unsigned*)ws; ws += M_ * 4;
    float*    tval    = (float*)ws;    ws += M_ * 4;
    unsigned* list    = (unsigned*)ws; ws += (size_t)M_ * NBY * SLICE * 4;  // 12.58 MB
    // total ws usage: ~121 MB
    const int docap = (ws_size >= (size_t)(ws - (char*)d_ws)) ? 1 : 0;

    const int histWords = M_ * (2048 + 2048 + 1024) + M_ * NBY; // hists + cnt
    k_zero   <<<dim3((histWords + 255) / 256), 256, 0, stream>>>(hist1, histWords);
    k_fwd    <<<dim3(M_, 5, 17),  256, 0, stream>>>(x, ll, det);
    k_hist1  <<<dim3(M_, NBY),    256, 0, stream>>>(det, hist1);
    k_sel2048<<<dim3(M_),         256, 0, stream>>>(hist1, nullptr, selBin1, rank1);
    k_hist2  <<<dim3(M_, NBY),    256, 0, stream>>>(det, selBin1, hist2, cnt, list, docap);
    k_sel2048<<<dim3(M_),         256, 0, stream>>>(hist2, rank1, selBin2, rank2);
    k_hist3  <<<dim3(M_, NBY),    256, 0, stream>>>(det, selBin1, selBin2, cnt, list, docap, hist3);
    k_sel3   <<<dim3(M_),         256, 0, stream>>>(hist3, rank2, selBin1, selBin2, tval);
    k_inv    <<<dim3(M_, 8, 16),  256, 0, stream>>>(ll, det, tval, out);
}

// Round 6
// 462.743 us; speedup vs baseline: 3.1024x; 1.0190x over previous
//
#include <hip/hip_runtime.h>
#include <math.h>

// Problem constants
#define B_   32
#define H_   512
#define W_   512
#define C_   3
#define M_   96          // B_*C_
#define NW_  263         // floor((512+15)/2)
#define NH_  263
#define DETPER 69169     // 263*263
#define DETTOT 207507    // 3*DETPER
#define DETSTRIDE 207508 // padded to multiple of 4 for float4 alignment
#define NVEC 51876       // DETTOT/4 (floor); tail = 3 elements
#define KRANK  103753u   // (DETTOT-1)/2, 0-based median rank

#define SXS 144          // sX row stride (floats)
#define CR  12           // sX chunk rows (46 = 12+12+12+10)

// db8 reconstruction filters (pre-derived; dec filters are reversed versions,
// and the reference's conv reduces to: ca[j] = sum_k xe[2j+k]*rec_lo[k])
__device__ __constant__ float RLO[16] = {
    0.05441584224308161f,  0.3128715909144659f,   0.6756307362980128f,
    0.5853546836548691f,  -0.015829105256023893f, -0.2840155429624281f,
    0.00047248457399797254f, 0.128747426620186f,  -0.01736930100202211f,
   -0.04408825393106472f,  0.013981027917015516f,  0.008746094047015655f,
   -0.00487035299301066f, -0.0003917403729959771f, 0.0006754494059985568f,
   -0.00011747678400228192f};
__device__ __constant__ float RHI[16] = {
   -0.00011747678400228192f, -0.0006754494059985568f, -0.0003917403729959771f,
    0.00487035299301066f,     0.008746094047015655f,  -0.013981027917015516f,
   -0.04408825393106472f,     0.01736930100202211f,    0.128747426620186f,
   -0.00047248457399797254f, -0.2840155429624281f,     0.015829105256023893f,
    0.5853546836548691f,     -0.6756307362980128f,     0.3128715909144659f,
   -0.05441584224308161f};

// Symmetric reflection of padded index q into [0, N)
__device__ __forceinline__ int refl(int q, int N) {
    if (q < 0)  return -q - 1;
    if (q >= N) return 2 * N - 1 - q;
    return q;
}

__device__ __forceinline__ float softthr(float v, float thr) {
    float a = fabsf(v) - thr;
    return a > 0.f ? copysignf(a, v) : 0.f;
}

// -------- zero-init for histogram region (no hipMemsetAsync in capture) --------
__global__ __launch_bounds__(256) void k_zero(unsigned* __restrict__ p, int n) {
    int i = blockIdx.x * 256 + threadIdx.x;
    if (i < n) p[i] = 0u;
}

// ---------------- Fused forward: row DWT + column DWT ----------------
// Round-2 body (162 us) + XCD-grouping swizzle: the 3 channel-blocks of each
// spatial tile get consecutive slots on the SAME XCD (delta-lin = 8), and
// adjacent tiles stay on one XCD, so the stride-3 x gathers and the 1.59x
// halo re-reads hit that XCD's L2 instead of re-fetching per XCD.
__global__ __launch_bounds__(256) void k_fwd(const float* __restrict__ x,
                                             float* __restrict__ ll,
                                             float* __restrict__ det) {
    __shared__ float sX[CR * SXS];                 // 6.75 KB, reused 4x
    __shared__ float sLO[46 * 64], sHI[46 * 64];   // 11.5 KB each
    // bijective swizzle of the 8160-block grid: 8160 = 8 xcd * 3 ch * 340 units
    const int lin = blockIdx.x + 96 * blockIdx.y + 480 * blockIdx.z;
    const int xcd = lin & 7, t = lin >> 3;
    const int c = t % 3, ul = t / 3;               // ul in [0,340)
    const int u = xcd * 340 + ul;                  // unit = (b, tile), 0..2719
    const int b = u / 85, r = u - 85 * b;          // 85 = 5 jw-tiles * 17 jh-tiles
    const int jw0 = (r % 5) * 64;
    const int jh0 = (r / 5) * 16;
    const int m = 3 * b + c;
    const int tid = threadIdx.x;
    const int prow0 = 2 * jh0 - 14, pcol0 = 2 * jw0 - 14;
    // chunked: stage CR padded-rows, row-DWT them, repeat (sX reused)
    for (int r0 = 0; r0 < 46; r0 += CR) {
        const int nr = (46 - r0) < CR ? (46 - r0) : CR;
        for (int l = tid; l < nr * 142; l += 256) {
            int rr = l / 142, cl = l - rr * 142;
            int h = refl(prow0 + r0 + rr, H_);
            int w = refl(pcol0 + cl, W_);
            sX[rr * SXS + cl] = x[((size_t)(b * H_ + h) * W_ + w) * C_ + c];
        }
        __syncthreads();
        for (int l = tid; l < nr * 64; l += 256) {
            int rr = l >> 6, j = l & 63;
            const float* px = &sX[rr * SXS + 2 * j];
            float al = 0.f, ah = 0.f;
#pragma unroll
            for (int k = 0; k < 16; ++k) {
                al = fmaf(px[k], RLO[k], al);
                ah = fmaf(px[k], RHI[k], ah);
            }
            sLO[(r0 + rr) * 64 + j] = al;
            sHI[(r0 + rr) * 64 + j] = ah;
        }
        __syncthreads();                           // sX reused next chunk
    }
    // column DWT: thread computes 4 consecutive jh (dy = 4*tg+d) at col tx,
    // loading the shared 22-row window once into registers.
    const int tx = tid & 63, tg = tid >> 6;
    const int jw = jw0 + tx;
    if (jw >= NW_) return;
    float vl[22], vh[22];
#pragma unroll
    for (int s = 0; s < 22; ++s) {
        int row = 8 * tg + s;                      // <= 45
        vl[s] = sLO[row * 64 + tx];
        vh[s] = sHI[row * 64 + tx];
    }
    float* llp = ll + (size_t)m * DETPER;
    float* dp  = det + (size_t)m * DETSTRIDE;
#pragma unroll
    for (int d = 0; d < 4; ++d) {
        int jh = jh0 + 4 * tg + d;
        if (jh >= NH_) continue;
        float a0 = 0.f, a1 = 0.f, a2 = 0.f, a3 = 0.f;
#pragma unroll
        for (int k = 0; k < 16; ++k) {
            float fl = vl[2 * d + k], fh = vh[2 * d + k];
            a0 = fmaf(fl, RLO[k], a0);
            a1 = fmaf(fl, RHI[k], a1);
            a2 = fmaf(fh, RLO[k], a2);
            a3 = fmaf(fh, RHI[k], a3);
        }
        size_t o = (size_t)jh * NW_ + jw;
        llp[o] = a0;                               // LL
        dp[o] = a1;                                // LH
        dp[DETPER + o] = a2;                       // HL
        dp[2 * DETPER + o] = a3;                   // HH
    }
}

// ---------------- Median: 3-pass radix histogram refinement over det ----------
// (round-2 plain scans — the capture variants of rounds 3-5 were all net losses)
__global__ __launch_bounds__(256) void k_hist1(const float* __restrict__ det,
                                               unsigned* __restrict__ hist) {
    __shared__ unsigned h[2048];
    const int tid = threadIdx.x, m = blockIdx.x;
    for (int i = tid; i < 2048; i += 256) h[i] = 0u;
    __syncthreads();
    const float* dp = det + (size_t)m * DETSTRIDE;
    const float4* dp4 = (const float4*)dp;
    const int stride = gridDim.y * 256;
    for (int v = blockIdx.y * 256 + tid; v < NVEC; v += stride) {
        float4 f = dp4[v];
        atomicAdd(&h[__float_as_uint(fabsf(f.x)) >> 21], 1u);
        atomicAdd(&h[__float_as_uint(fabsf(f.y)) >> 21], 1u);
        atomicAdd(&h[__float_as_uint(fabsf(f.z)) >> 21], 1u);
        atomicAdd(&h[__float_as_uint(fabsf(f.w)) >> 21], 1u);
    }
    if (blockIdx.y == 0 && tid < DETTOT - 4 * NVEC) {
        unsigned u = __float_as_uint(fabsf(dp[4 * NVEC + tid]));
        atomicAdd(&h[u >> 21], 1u);
    }
    __syncthreads();
    for (int i = tid; i < 2048; i += 256)
        if (h[i]) atomicAdd(&hist[m * 2048 + i], h[i]);
}

__global__ __launch_bounds__(256) void k_hist2(const float* __restrict__ det,
                                               const int* __restrict__ selBin1,
                                               unsigned* __restrict__ hist) {
    __shared__ unsigned h[2048];
    const int tid = threadIdx.x, m = blockIdx.x;
    const unsigned target = (unsigned)selBin1[m];
    for (int i = tid; i < 2048; i += 256) h[i] = 0u;
    __syncthreads();
    const float* dp = det + (size_t)m * DETSTRIDE;
    const float4* dp4 = (const float4*)dp;
    const int stride = gridDim.y * 256;
    for (int v = blockIdx.y * 256 + tid; v < NVEC; v += stride) {
        float4 f = dp4[v];
        unsigned a = __float_as_uint(fabsf(f.x));
        unsigned b = __float_as_uint(fabsf(f.y));
        unsigned c = __float_as_uint(fabsf(f.z));
        unsigned d = __float_as_uint(fabsf(f.w));
        if ((a >> 21) == target) atomicAdd(&h[(a >> 10) & 0x7FFu], 1u);
        if ((b >> 21) == target) atomicAdd(&h[(b >> 10) & 0x7FFu], 1u);
        if ((c >> 21) == target) atomicAdd(&h[(c >> 10) & 0x7FFu], 1u);
        if ((d >> 21) == target) atomicAdd(&h[(d >> 10) & 0x7FFu], 1u);
    }
    if (blockIdx.y == 0 && tid < DETTOT - 4 * NVEC) {
        unsigned u = __float_as_uint(fabsf(dp[4 * NVEC + tid]));
        if ((u >> 21) == target) atomicAdd(&h[(u >> 10) & 0x7FFu], 1u);
    }
    __syncthreads();
    for (int i = tid; i < 2048; i += 256)
        if (h[i]) atomicAdd(&hist[m * 2048 + i], h[i]);
}

__global__ __launch_bounds__(256) void k_hist3(const float* __restrict__ det,
                                               const int* __restrict__ selBin1,
                                               const int* __restrict__ selBin2,
                                               unsigned* __restrict__ hist) {
    __shared__ unsigned h[1024];
    const int tid = threadIdx.x, m = blockIdx.x;
    const unsigned target = ((unsigned)selBin1[m] << 11) | (unsigned)selBin2[m];
    for (int i = tid; i < 1024; i += 256) h[i] = 0u;
    __syncthreads();
    const float* dp = det + (size_t)m * DETSTRIDE;
    const float4* dp4 = (const float4*)dp;
    const int stride = gridDim.y * 256;
    for (int v = blockIdx.y * 256 + tid; v < NVEC; v += stride) {
        float4 f = dp4[v];
        unsigned a = __float_as_uint(fabsf(f.x));
        unsigned b = __float_as_uint(fabsf(f.y));
        unsigned c = __float_as_uint(fabsf(f.z));
        unsigned d = __float_as_uint(fabsf(f.w));
        if ((a >> 10) == target) atomicAdd(&h[a & 0x3FFu], 1u);
        if ((b >> 10) == target) atomicAdd(&h[b & 0x3FFu], 1u);
        if ((c >> 10) == target) atomicAdd(&h[c & 0x3FFu], 1u);
        if ((d >> 10) == target) atomicAdd(&h[d & 0x3FFu], 1u);
    }
    if (blockIdx.y == 0 && tid < DETTOT - 4 * NVEC) {
        unsigned u = __float_as_uint(fabsf(dp[4 * NVEC + tid]));
        if ((u >> 10) == target) atomicAdd(&h[u & 0x3FFu], 1u);
    }
    __syncthreads();
    for (int i = tid; i < 1024; i += 256)
        if (h[i]) atomicAdd(&hist[m * 1024 + i], h[i]);
}

// Cooperative select: find bin of LDS histogram (nb multiple of 256) containing `rank`
__device__ int histSelect(unsigned* hist, int nb, unsigned rank, unsigned* rem) {
    __shared__ unsigned ps[256];
    __shared__ int s_bin;
    __shared__ unsigned s_rem;
    const int tid = threadIdx.x;
    if (tid == 0) { s_bin = 0; s_rem = 0; }      // deterministic fallback
    const int per = nb >> 8;
    unsigned s = 0;
    for (int i = 0; i < per; ++i) s += hist[tid * per + i];
    ps[tid] = s;
    __syncthreads();
    for (int off = 1; off < 256; off <<= 1) {
        unsigned v = ps[tid];
        unsigned add = (tid >= off) ? ps[tid - off] : 0u;
        __syncthreads();
        ps[tid] = v + add;
        __syncthreads();
    }
    unsigned incl = ps[tid], excl = incl - s;
    if (rank >= excl && rank < incl) {
        unsigned cum = excl;
        for (int i = 0; i < per; ++i) {
            unsigned c = hist[tid * per + i];
            if (cum + c > rank) { s_bin = tid * per + i; s_rem = rank - cum; break; }
            cum += c;
        }
    }
    __syncthreads();
    int rbin = s_bin;
    unsigned rr = s_rem;
    __syncthreads();   // protect shared reuse across calls
    *rem = rr;
    return rbin;
}

__global__ __launch_bounds__(256) void k_sel2048(const unsigned* __restrict__ hist,
                                                 const unsigned* __restrict__ rankIn, // null => KRANK
                                                 int* __restrict__ selBin,
                                                 unsigned* __restrict__ rankOut) {
    __shared__ unsigned h[2048];
    const int m = blockIdx.x, tid = threadIdx.x;
    for (int i = tid; i < 2048; i += 256) h[i] = hist[m * 2048 + i];
    __syncthreads();
    unsigned rank = rankIn ? rankIn[m] : KRANK;
    unsigned rem;
    int bin = histSelect(h, 2048, rank, &rem);
    if (tid == 0) { selBin[m] = bin; rankOut[m] = rem; }
}

__global__ __launch_bounds__(256) void k_sel3(const unsigned* __restrict__ hist,
                                              const unsigned* __restrict__ rankIn,
                                              const int* __restrict__ selBin1,
                                              const int* __restrict__ selBin2,
                                              float* __restrict__ tval) {
    __shared__ unsigned h[1024];
    const int m = blockIdx.x, tid = threadIdx.x;
    for (int i = tid; i < 1024; i += 256) h[i] = hist[m * 1024 + i];
    __syncthreads();
    unsigned rem;
    int low = histSelect(h, 1024, rankIn[m], &rem);
    if (tid == 0) {
        unsigned bits = ((unsigned)selBin1[m] << 21) | ((unsigned)selBin2[m] << 10) | (unsigned)low;
        double med = (double)__uint_as_float(bits);
        // t = median/0.6745 * sqrt(2*ln(512*512))
        tval[m] = (float)(med / 0.6745 * 4.995327667046959);
    }
}

// ---------------- Fused inverse: soft-threshold + column IDWT + row IDWT ------
// v3 body + XCD-grouping swizzle: the 3 channel-blocks writing the same NHWC
// output sectors (stride-3 interleave) land on one XCD, so lines become fully
// dirty in a single L2 and write back once instead of 3 masked partial writes.
__global__ __launch_bounds__(256) void k_inv(const float* __restrict__ ll,
                                             const float* __restrict__ det,
                                             const float* __restrict__ tval,
                                             float* __restrict__ out) {
    __shared__ float sLL[23 * 40], sLH[23 * 40], sHL[23 * 40], sHH[23 * 40];
    __shared__ float sRL[32 * 40], sRH[32 * 40];
    // bijective swizzle of the 12288-block grid: 12288 = 8 xcd * 3 ch * 512 units
    const int lin = blockIdx.x + 96 * blockIdx.y + 768 * blockIdx.z;
    const int xcd = lin & 7, t = lin >> 3;
    const int c = t % 3, ul = t / 3;             // ul in [0,512)
    const int u = xcd * 512 + ul;                // unit = (b, w-tile, t-tile)
    const int b = u >> 7, r = u & 127;           // 128 = 8 w-tiles * 16 t-tiles
    const int w0 = (r & 7) * 64;
    const int t0 = (r >> 3) * 32;
    const int m = 3 * b + c;
    const int tid = threadIdx.x;
    const float thr = tval[m];
    const int jW0 = w0 >> 1, s0 = t0 >> 1;
    const float* llp = ll + (size_t)m * DETPER;
    const float* dp  = det + (size_t)m * DETSTRIDE;
    for (int l = tid; l < 23 * 39; l += 256) {
        int rr = l / 39, cc = l - rr * 39;
        size_t o = (size_t)(s0 + rr) * NW_ + (jW0 + cc);
        int li = rr * 40 + cc;
        sLL[li] = llp[o];
        sLH[li] = softthr(dp[o], thr);
        sHL[li] = softthr(dp[DETPER + o], thr);
        sHH[li] = softthr(dp[2 * DETPER + o], thr);
    }
    __syncthreads();
    // column IDWT: item (s in [0,16), q in [0,10)) -> output rows 2s,2s+1,
    // cols 4q..4q+3. Source rows s..s+7 (<=22); col 39 never read downstream.
    for (int l = tid; l < 160; l += 256) {
        int s = l / 10, q = l - 10 * (l / 10);
        float4 aL0 = make_float4(0.f, 0.f, 0.f, 0.f), aL1 = aL0, aH0 = aL0, aH1 = aL0;
#pragma unroll
        for (int a = 0; a < 8; ++a) {
            int li = (s + 7 - a) * 40 + 4 * q;
            float4 vLL = *(const float4*)&sLL[li];
            float4 vLH = *(const float4*)&sLH[li];
            float4 vHL = *(const float4*)&sHL[li];
            float4 vHH = *(const float4*)&sHH[li];
            float w00 = RLO[2 * a],     h00 = RHI[2 * a];       // parity r=0
            float w01 = RLO[2 * a + 1], h01 = RHI[2 * a + 1];   // parity r=1
            aL0.x = fmaf(vLL.x, w00, fmaf(vLH.x, h00, aL0.x));
            aL0.y = fmaf(vLL.y, w00, fmaf(vLH.y, h00, aL0.y));
            aL0.z = fmaf(vLL.z, w00, fmaf(vLH.z, h00, aL0.z));
            aL0.w = fmaf(vLL.w, w00, fmaf(vLH.w, h00, aL0.w));
            aL1.x = fmaf(vLL.x, w01, fmaf(vLH.x, h01, aL1.x));
            aL1.y = fmaf(vLL.y, w01, fmaf(vLH.y, h01, aL1.y));
            aL1.z = fmaf(vLL.z, w01, fmaf(vLH.z, h01, aL1.z));
            aL1.w = fmaf(vLL.w, w01, fmaf(vLH.w, h01, aL1.w));
            aH0.x = fmaf(vHL.x, w00, fmaf(vHH.x, h00, aH0.x));
            aH0.y = fmaf(vHL.y, w00, fmaf(vHH.y, h00, aH0.y));
            aH0.z = fmaf(vHL.z, w00, fmaf(vHH.z, h00, aH0.z));
            aH0.w = fmaf(vHL.w, w00, fmaf(vHH.w, h00, aH0.w));
            aH1.x = fmaf(vHL.x, w01, fmaf(vHH.x, h01, aH1.x));
            aH1.y = fmaf(vHL.y, w01, fmaf(vHH.y, h01, aH1.y));
            aH1.z = fmaf(vHL.z, w01, fmaf(vHH.z, h01, aH1.z));
            aH1.w = fmaf(vHL.w, w01, fmaf(vHH.w, h01, aH1.w));
        }
        *(float4*)&sRL[(2 * s) * 40 + 4 * q]     = aL0;
        *(float4*)&sRL[(2 * s + 1) * 40 + 4 * q] = aL1;
        *(float4*)&sRH[(2 * s) * 40 + 4 * q]     = aH0;
        *(float4*)&sRH[(2 * s + 1) * 40 + 4 * q] = aH1;
    }
    __syncthreads();
    // row IDWT + NHWC store: thread (tr = tid>>3, jg = tid&7) produces the 8
    // outputs wloc = 8jg..8jg+7 from words [4jg, 4jg+10] of sRL/sRH (3 b128 each).
    {
        const int tr = tid >> 3, jg = tid & 7;
        const float4* pl = (const float4*)&sRL[tr * 40 + 4 * jg];  // 16B aligned
        const float4* ph = (const float4*)&sRH[tr * 40 + 4 * jg];
        float4 L0 = pl[0], L1 = pl[1], L2 = pl[2];
        float4 K0 = ph[0], K1 = ph[1], K2 = ph[2];
        float rl[12] = {L0.x,L0.y,L0.z,L0.w, L1.x,L1.y,L1.z,L1.w, L2.x,L2.y,L2.z,L2.w};
        float rh[12] = {K0.x,K0.y,K0.z,K0.w, K1.x,K1.y,K1.z,K1.w, K2.x,K2.y,K2.z,K2.w};
        size_t obase = ((size_t)(b * H_ + (t0 + tr)) * W_ + (w0 + 8 * jg)) * C_ + c;
#pragma unroll
        for (int u2 = 0; u2 < 4; ++u2) {
#pragma unroll
            for (int rp = 0; rp < 2; ++rp) {
                float acc = 0.f;
#pragma unroll
                for (int a = 0; a < 8; ++a) {
                    int sdx = u2 + 7 - a;        // in [u2, u2+7] subset of [0,10]
                    acc = fmaf(rl[sdx], RLO[2 * a + rp], fmaf(rh[sdx], RHI[2 * a + rp], acc));
                }
                out[obase + (size_t)(2 * u2 + rp) * C_] = acc;
            }
        }
    }
}

extern "C" void kernel_launch(void* const* d_in, const int* in_sizes, int n_in,
                              void* d_out, int out_size, void* d_ws, size_t ws_size,
                              hipStream_t stream) {
    const float* x = (const float*)d_in[0];
    float* out = (float*)d_out;

    char* ws = (char*)d_ws;
    float* ll  = (float*)ws; ws += (size_t)M_ * DETPER * 4;     // 26.56 MB
    float* det = (float*)ws; ws += (size_t)M_ * DETSTRIDE * 4;  // 79.68 MB  [m][{lh,hl,hh}][DETPER]
    unsigned* hist1 = (unsigned*)ws; ws += (size_t)M_ * 2048 * 4;
    unsigned* hist2 = (unsigned*)ws; ws += (size_t)M_ * 2048 * 4;
    unsigned* hist3 = (unsigned*)ws; ws += (size_t)M_ * 1024 * 4;
    int*      selBin1 = (int*)ws;      ws += M_ * 4;
    int*      selBin2 = (int*)ws;      ws += M_ * 4;
    unsigned* rank1   = (unsigned*)ws; ws += M_ * 4;
    unsigned* rank2   = (unsigned*)ws; ws += M_ * 4;
    float*    tval    = (float*)ws;    ws += M_ * 4;
    // total ws usage: ~108.2 MB

    const int histWords = M_ * (2048 + 2048 + 1024);            // 491,520
    k_zero   <<<dim3((histWords + 255) / 256), 256, 0, stream>>>(hist1, histWords);
    k_fwd    <<<dim3(M_, 5, 17),  256, 0, stream>>>(x, ll, det);
    k_hist1  <<<dim3(M_, 16),     256, 0, stream>>>(det, hist1);
    k_sel2048<<<dim3(M_),         256, 0, stream>>>(hist1, nullptr, selBin1, rank1);
    k_hist2  <<<dim3(M_, 16),     256, 0, stream>>>(det, selBin1, hist2);
    k_sel2048<<<dim3(M_),         256, 0, stream>>>(hist2, rank1, selBin2, rank2);
    k_hist3  <<<dim3(M_, 16),     256, 0, stream>>>(det, selBin1, selBin2, hist3);
    k_sel3   <<<dim3(M_),         256, 0, stream>>>(hist3, rank2, selBin1, selBin2, tval);
    k_inv    <<<dim3(M_, 8, 16),  256, 0, stream>>>(ll, det, tval, out);
}